// Round 1
// baseline (201.077 us; speedup 1.0000x reference)
//
#include <hip/hip_runtime.h>
#include <hip/hip_bf16.h>

// LSTM cell, B=8192, IN=1024, H=1024.
// gates[8192,4096] = [x|h_prev] @ [Wf|Wi|Wu|Wo] + b ; fused epilogue -> h_t, c_t.
// Strategy: bf16 MFMA GEMM (threshold 7.8e-2 allows bf16), m97-style 128^2 tile,
// pack-time XOR swizzle so global_load_lds (linear dest) + swizzled ds_read_b128.

typedef __attribute__((ext_vector_type(8))) short short8;   // 8 bf16 = 4 VGPRs
typedef __attribute__((ext_vector_type(4))) float f32x4;

#define GLOBAL_AS __attribute__((address_space(1)))
#define LDS_AS    __attribute__((address_space(3)))

__device__ __forceinline__ void load_lds16(const void* g, void* l) {
  // 16B/lane direct global->LDS DMA; LDS dest = wave-uniform base + lane*16
  __builtin_amdgcn_global_load_lds((const GLOBAL_AS unsigned int*)g,
                                   (LDS_AS unsigned int*)l, 16, 0, 0);
}

__device__ __forceinline__ unsigned short f2bf(float f) {
  unsigned int u = __float_as_uint(f);
  unsigned int r = (u + 0x7FFFu + ((u >> 16) & 1u)) >> 16;  // RNE
  return (unsigned short)r;
}

__device__ __forceinline__ float sigf(float x) {
  return 1.0f / (1.0f + __expf(-x));
}
__device__ __forceinline__ float tanh_fast(float x) {
  // 1 - 2/(e^{2x}+1): exact at +-inf, branch-free
  return 1.0f - 2.0f / (__expf(2.0f * x) + 1.0f);
}

// ---------------------------------------------------------------------------
// Pack A = [x | h_prev] -> bf16 [8192][2048], 16B chunks XOR-swizzled within
// each 128B (BK=64) block: dest_chunk = (c & ~7) | ((c&7) ^ (row&7)).
// grid 8192 x 256 threads; thread = one 8-elem chunk (32B read, 16B write).
// ---------------------------------------------------------------------------
__global__ void pack_a_kernel(const float* __restrict__ x,
                              const float* __restrict__ h,
                              unsigned short* __restrict__ Apk) {
  int t = blockIdx.x * 256 + threadIdx.x;
  int row = t >> 8;        // 0..8191
  int c   = t & 255;       // chunk of 8 bf16 within row (2048 = 256 chunks)
  int k   = c << 3;
  const float* src = (k < 1024) ? (x + (size_t)row * 1024 + k)
                                : (h + (size_t)row * 1024 + (k - 1024));
  float4 f0 = ((const float4*)src)[0];
  float4 f1 = ((const float4*)src)[1];
  union { unsigned short us[8]; uint4 v; } u;
  u.us[0] = f2bf(f0.x); u.us[1] = f2bf(f0.y);
  u.us[2] = f2bf(f0.z); u.us[3] = f2bf(f0.w);
  u.us[4] = f2bf(f1.x); u.us[5] = f2bf(f1.y);
  u.us[6] = f2bf(f1.z); u.us[7] = f2bf(f1.w);
  int dc = (c & ~7) | ((c & 7) ^ (row & 7));
  *(uint4*)(Apk + (size_t)row * 2048 + dc * 8) = u.v;
}

// ---------------------------------------------------------------------------
// Pack W^T: Wp[n][k] = W_g[k][n'], n = g*1024 + n', bf16, same chunk swizzle.
// grid 4096 blocks x 256 threads; block = (g, n-block of 256, k-chunk c).
// Reads coalesced along n (1KB per j); writes 16B scattered (acceptable, 16MB).
// ---------------------------------------------------------------------------
__global__ void pack_w_kernel(const float* __restrict__ W0,
                              const float* __restrict__ W1,
                              const float* __restrict__ W2,
                              const float* __restrict__ W3,
                              unsigned short* __restrict__ Wp) {
  int b  = blockIdx.x;
  int c  = b & 255;          // k-chunk (k = c*8 .. c*8+7)
  int nb = (b >> 8) & 3;     // n' block
  int g  = b >> 10;          // gate
  const float* Wg = (g == 0) ? W0 : (g == 1) ? W1 : (g == 2) ? W2 : W3;
  int np = nb * 256 + threadIdx.x;   // n' 0..1023
  int kbase = c << 3;
  union { unsigned short us[8]; uint4 v; } u;
#pragma unroll
  for (int j = 0; j < 8; ++j)
    u.us[j] = f2bf(Wg[(size_t)(kbase + j) * 1024 + np]);
  int n = (g << 10) + np;    // 0..4095
  int dc = (c & ~7) | ((c & 7) ^ (n & 7));
  *(uint4*)(Wp + (size_t)n * 2048 + dc * 8) = u.v;
}

// ---------------------------------------------------------------------------
// Fused GEMM + LSTM epilogue.
// Block: 256 thr = 4 waves (2x2). Tile: 128 M-rows x 32 h-cols x 4 gates
// (= 128x128 of the gates matrix). BK=64, K=2048 -> 32 iters.
// Each wave: 64 rows x 16 cols, all 4 gates -> acc[4][4] f32x4 (64 VGPRs).
// Epilogue is register-local: bias + sigmoid/tanh + c_prev combine.
// ---------------------------------------------------------------------------
__global__ __launch_bounds__(256) void lstm_gemm_kernel(
    const unsigned short* __restrict__ Apk,   // [8192][2048] bf16 swizzled
    const unsigned short* __restrict__ Wp,    // [4096][2048] bf16 swizzled (W^T)
    const float* __restrict__ c_prev,
    const float* __restrict__ bF, const float* __restrict__ bI,
    const float* __restrict__ bU, const float* __restrict__ bO,
    float* __restrict__ outH, float* __restrict__ outC) {
  __shared__ __align__(16) unsigned short Abuf[128 * 64];   // 16 KB
  __shared__ __align__(16) unsigned short Bbuf[128 * 64];   // 16 KB

  const int tid = threadIdx.x;
  const int l   = tid & 63;
  const int w   = tid >> 6;
  const int wr  = w >> 1;          // wave M index (0..1)
  const int wc  = w & 1;           // wave N index (0..1)

  // XCD-bijective swizzle: 2048 blocks = 8 XCDs x 256
  int bid = blockIdx.x;
  int wg  = ((bid & 7) << 8) | (bid >> 3);
  int mblk = wg >> 5;              // 0..63
  int nblk = wg & 31;              // 0..31
  int brow  = mblk << 7;           // M base
  int ncol0 = nblk << 5;           // h-col base (0..1023 step 32)

  f32x4 acc[4][4];                 // [gate][m-frag]
#pragma unroll
  for (int g = 0; g < 4; ++g)
#pragma unroll
    for (int m = 0; m < 4; ++m) acc[g][m] = (f32x4)0.0f;

  const int seg0  = w << 2;        // wave's first 1KB LDS segment
  const int rlane = l >> 3;        // row within 8-row segment
  const int clane = l & 7;         // 16B chunk within 128B row

  // A: global row = brow + (seg0+i)*8 + rlane, chunk clane (pre-swizzled global)
  const unsigned short* agbase =
      Apk + (size_t)(brow + seg0 * 8 + rlane) * 2048 + clane * 8;

  for (int kt = 0; kt < 32; ++kt) {
    const int kofs = kt << 6;   // ushort offset (=128B)
    // stage A tile: 128 rows x 64 bf16
#pragma unroll
    for (int i = 0; i < 4; ++i) {
      load_lds16(agbase + (size_t)i * 8 * 2048 + kofs, &Abuf[(seg0 + i) * 512]);
    }
    // stage B tile: rows j=0..127 -> Wp row (j>>5)*1024 + ncol0 + (j&31)
#pragma unroll
    for (int i = 0; i < 4; ++i) {
      int j = (seg0 + i) * 8 + rlane;
      int grow = ((j >> 5) << 10) + ncol0 + (j & 31);
      load_lds16(Wp + (size_t)grow * 2048 + kofs + clane * 8,
                 &Bbuf[(seg0 + i) * 512]);
    }
    __syncthreads();

#pragma unroll
    for (int kk = 0; kk < 2; ++kk) {
      const int ck = (kk << 2) | (l >> 4);      // k-chunk within BK (0..7)
      const int sc = ck ^ (l & 7);              // unswizzle
      short8 a[4], bfr[4];
#pragma unroll
      for (int m = 0; m < 4; ++m) {
        int row = wr * 64 + m * 16 + (l & 15);
        a[m] = *(const short8*)&Abuf[row * 64 + sc * 8];
      }
#pragma unroll
      for (int g = 0; g < 4; ++g) {
        int j = g * 32 + wc * 16 + (l & 15);
        bfr[g] = *(const short8*)&Bbuf[j * 64 + sc * 8];
      }
#pragma unroll
      for (int g = 0; g < 4; ++g)
#pragma unroll
        for (int m = 0; m < 4; ++m)
          acc[g][m] = __builtin_amdgcn_mfma_f32_16x16x32_bf16(
              a[m], bfr[g], acc[g][m], 0, 0, 0);
    }
    __syncthreads();
  }

  // Epilogue: lane l, reg r -> row = base + m*16 + (l>>4)*4 + r, col = l&15
  const int colh = ncol0 + wc * 16 + (l & 15);
  const float biasF = bF[colh], biasI = bI[colh];
  const float biasU = bU[colh], biasO = bO[colh];
  const int rowbase = brow + wr * 64 + ((l >> 4) << 2);
#pragma unroll
  for (int m = 0; m < 4; ++m) {
#pragma unroll
    for (int r = 0; r < 4; ++r) {
      int row = rowbase + m * 16 + r;
      size_t idx = (size_t)row * 1024 + colh;
      float f  = sigf(acc[0][m][r] + biasF);
      float i_ = sigf(acc[1][m][r] + biasI);
      float g_ = tanh_fast(acc[2][m][r] + biasU);
      float o_ = sigf(acc[3][m][r] + biasO);
      float cp = c_prev[idx];
      float cn = cp * f + i_ * g_;
      outH[idx] = o_ * tanh_fast(cn);
      outC[idx] = cn;
    }
  }
}

// ---------------------------------------------------------------------------
extern "C" void kernel_launch(void* const* d_in, const int* in_sizes, int n_in,
                              void* d_out, int out_size, void* d_ws, size_t ws_size,
                              hipStream_t stream) {
  const float* x      = (const float*)d_in[0];
  const float* h_prev = (const float*)d_in[1];
  const float* c_prev = (const float*)d_in[2];
  // d_in[3] = embed (unused by reference forward)
  const float* Wf = (const float*)d_in[4];
  const float* bf = (const float*)d_in[5];
  const float* Wi = (const float*)d_in[6];
  const float* bi = (const float*)d_in[7];
  const float* Wu = (const float*)d_in[8];
  const float* bu = (const float*)d_in[9];
  const float* Wo = (const float*)d_in[10];
  const float* bo = (const float*)d_in[11];

  unsigned short* Apk = (unsigned short*)d_ws;                       // 32 MB
  unsigned short* Wp  = (unsigned short*)((char*)d_ws + (size_t)8192 * 2048 * 2); // 16 MB

  pack_a_kernel<<<8192, 256, 0, stream>>>(x, h_prev, Apk);
  pack_w_kernel<<<4096, 256, 0, stream>>>(Wf, Wi, Wu, Wo, Wp);

  float* outH = (float*)d_out;
  float* outC = outH + (size_t)8192 * 1024;
  lstm_gemm_kernel<<<2048, 256, 0, stream>>>(Apk, Wp, c_prev,
                                             bf, bi, bu, bo, outH, outC);
}

// Round 2
// 170.487 us; speedup vs baseline: 1.1794x; 1.1794x over previous
//
#include <hip/hip_runtime.h>
#include <hip/hip_bf16.h>

// LSTM cell, B=8192, IN=1024, H=1024.
// gates[8192,4096] = [x|h_prev] @ [Wf|Wi|Wu|Wo] + b ; fused epilogue -> h_t, c_t.
// Round 2: 256^2-tile 8-phase pipelined GEMM (T3+T4 counted vmcnt, T5 setprio,
// T2-style swizzle via pre-swizzled global src), gate-interleaved N so the
// LSTM epilogue stays register-local.

typedef __attribute__((ext_vector_type(8))) short short8;   // 8 bf16
typedef __attribute__((ext_vector_type(4))) float f32x4;

#define GLOBAL_AS __attribute__((address_space(1)))
#define LDS_AS    __attribute__((address_space(3)))

__device__ __forceinline__ void load_lds16(const void* g, void* l) {
  // 16B/lane global->LDS DMA; LDS dest = wave-uniform base + lane*16 (linear)
  __builtin_amdgcn_global_load_lds((const GLOBAL_AS unsigned int*)g,
                                   (LDS_AS unsigned int*)l, 16, 0, 0);
}

__device__ __forceinline__ unsigned short f2bf(float f) {
  unsigned int u = __float_as_uint(f);
  return (unsigned short)((u + 0x7FFFu + ((u >> 16) & 1u)) >> 16);  // RNE
}
__device__ __forceinline__ float sigf(float x) { return 1.0f / (1.0f + __expf(-x)); }
__device__ __forceinline__ float tanh_fast(float x) {
  return 1.0f - 2.0f / (__expf(2.0f * x) + 1.0f);
}

// ---------------------------------------------------------------------------
// Pack A = [x | h_prev] -> bf16 [8192][2048], linear (no pack-time swizzle;
// the LDS swizzle is applied via per-lane staging source addresses).
// ---------------------------------------------------------------------------
__global__ void pack_a_kernel(const float* __restrict__ x,
                              const float* __restrict__ h,
                              unsigned short* __restrict__ Apk) {
  int t = blockIdx.x * 256 + threadIdx.x;
  int row = t >> 8;
  int c   = t & 255;
  int k   = c << 3;
  const float* src = (k < 1024) ? (x + (size_t)row * 1024 + k)
                                : (h + (size_t)row * 1024 + (k - 1024));
  float4 f0 = ((const float4*)src)[0];
  float4 f1 = ((const float4*)src)[1];
  union { unsigned short us[8]; uint4 v; } u;
  u.us[0] = f2bf(f0.x); u.us[1] = f2bf(f0.y);
  u.us[2] = f2bf(f0.z); u.us[3] = f2bf(f0.w);
  u.us[4] = f2bf(f1.x); u.us[5] = f2bf(f1.y);
  u.us[6] = f2bf(f1.z); u.us[7] = f2bf(f1.w);
  *(uint4*)(Apk + (size_t)row * 2048 + c * 8) = u.v;
}

// ---------------------------------------------------------------------------
// Pack W^T: Wp[n][k] = W_g[k][n'], n = g*1024 + n', bf16 linear.
// ---------------------------------------------------------------------------
__global__ void pack_w_kernel(const float* __restrict__ W0,
                              const float* __restrict__ W1,
                              const float* __restrict__ W2,
                              const float* __restrict__ W3,
                              unsigned short* __restrict__ Wp) {
  int b  = blockIdx.x;
  int c  = b & 255;
  int nb = (b >> 8) & 3;
  int g  = b >> 10;
  const float* Wg = (g == 0) ? W0 : (g == 1) ? W1 : (g == 2) ? W2 : W3;
  int np = nb * 256 + threadIdx.x;
  int kbase = c << 3;
  union { unsigned short us[8]; uint4 v; } u;
#pragma unroll
  for (int j = 0; j < 8; ++j)
    u.us[j] = f2bf(Wg[(size_t)(kbase + j) * 1024 + np]);
  int n = (g << 10) + np;
  *(uint4*)(Wp + (size_t)n * 2048 + c * 8) = u.v;
}

// ---------------------------------------------------------------------------
// 8-phase GEMM + LSTM epilogue.
// Block: 512 thr = 8 waves (2M x 4N). Tile: 256 M-rows x 256 packed cols
// (= 64 h-cols x 4 gates, packed col p = (h>>4)*64 + g*16 + (h&15)).
// BK=64 split into K-half slots of 32. LDS ring: 4 A slots + 4 B slots
// (buf0K0, buf0K1, buf1K0, buf1K1), 16 KB each = 128 KB dynamic LDS.
// Iteration = 2 K-tiles = 4 pairs x 2 phases. Pair j consumes slot j;
// prefetch (L=3 slot lead): pair0->S3(tile 2i+1 K1), pair1->S0(2i+2 K0),
// pair2->S1(2i+2 K1), pair3->S2(2i+3 K0). Waits: vmcnt(8)@(1,1),
// vmcnt(8)@(2,1), vmcnt(4)@(3,1) — never drained to 0 in the loop.
// ---------------------------------------------------------------------------
#define MFMA16(va, vb, vc) __builtin_amdgcn_mfma_f32_16x16x32_bf16(va, vb, vc, 0, 0, 0)

// J: slot/pair index 0..3 ; Q: m-half 0/1 ; KTP: prefetch K-tile (runtime expr)
// PSLOT: dest slot index for prefetch ; WAITN: -1 none, 8 or 4
#define PHASE(J, Q, KTP, PSLOT, WAITN)                                         \
  {                                                                            \
    const int slotUS = (J) * 8192;                                             \
    short8 av[4];                                                              \
    _Pragma("unroll")                                                          \
    for (int mm = 0; mm < 4; ++mm)                                             \
      av[mm] = *(const short8*)&LDSu[slotUS + aRdBase + ((Q) * 4 + mm) * 512]; \
    if ((Q) == 0) {                                                            \
      _Pragma("unroll")                                                        \
      for (int gg = 0; gg < 4; ++gg)                                           \
        bv[gg] = *(const short8*)&LDSu[32768 + slotUS + bRdBase + gg * 512];   \
    }                                                                          \
    int ktp = (KTP); ktp = (ktp > 31) ? 31 : ktp;                              \
    const int srcOfs = ktp * 64 + ((PSLOT) & 1) * 32;                          \
    const int pbase = (PSLOT) * 8192;                                          \
    if ((Q) == 0) {                                                            \
      load_lds16(aSrc0 + srcOfs, &LDSu[pbase + wv * 512]);                     \
      load_lds16(aSrc1 + srcOfs, &LDSu[pbase + 4096 + wv * 512]);              \
    } else {                                                                   \
      load_lds16(bSrc0 + srcOfs, &LDSu[32768 + pbase + wv * 512]);             \
      load_lds16(bSrc1 + srcOfs, &LDSu[32768 + pbase + 4096 + wv * 512]);      \
    }                                                                          \
    asm volatile("s_barrier" ::: "memory");                                    \
    __builtin_amdgcn_s_setprio(1);                                             \
    _Pragma("unroll")                                                          \
    for (int mm = 0; mm < 4; ++mm) {                                           \
      _Pragma("unroll")                                                        \
      for (int gg = 0; gg < 4; ++gg)                                           \
        acc[(Q) * 4 + mm][gg] = MFMA16(av[mm], bv[gg], acc[(Q) * 4 + mm][gg]); \
    }                                                                          \
    __builtin_amdgcn_s_setprio(0);                                             \
    if ((WAITN) == 8) asm volatile("s_waitcnt vmcnt(8)" ::: "memory");         \
    if ((WAITN) == 4) asm volatile("s_waitcnt vmcnt(4)" ::: "memory");         \
    asm volatile("s_barrier" ::: "memory");                                    \
  }

__global__ __launch_bounds__(512, 2) void lstm_gemm_kernel(
    const unsigned short* __restrict__ Apk,   // [8192][2048] bf16
    const unsigned short* __restrict__ Wp,    // [4096][2048] bf16 (W^T)
    const float* __restrict__ c_prev,
    const float* __restrict__ bF, const float* __restrict__ bI,
    const float* __restrict__ bU, const float* __restrict__ bO,
    float* __restrict__ outH, float* __restrict__ outC) {
  extern __shared__ unsigned short LDSu[];    // 65536 ushorts = 128 KB

  const int tid = threadIdx.x;
  const int l   = tid & 63;
  const int wv  = tid >> 6;        // wave 0..7
  const int wr  = wv >> 2;         // wave M index 0..1
  const int wc  = wv & 3;          // wave N index 0..3

  // XCD-bijective swizzle: 512 blocks = 8 XCDs x 64
  int bid = blockIdx.x;
  int wg  = ((bid & 7) << 6) | (bid >> 3);
  const int mblk = wg >> 4;        // 0..31
  const int nblk = wg & 15;        // 0..15
  const int brow = mblk << 8;      // M base (x256)

  // --- ds_read addressing (ushort units). Rows are 32 us (=64B, one K-half).
  // swizzled chunk sc = cg ^ ((ldsrow>>1)&3); 2-way bank aliasing only (free).
  const int rl  = l & 15;
  const int cg  = l >> 4;                       // k-chunk group 0..3
  const int sc  = cg ^ ((rl >> 1) & 3);
  const int aRdBase = (wr * 128 + rl) * 32 + sc * 8;
  const int bRdBase = (wc * 64 + rl) * 32 + sc * 8;

  // --- staging source addressing: LDS row = qq*128 + wv*16 + (l>>2), linear
  // dest; global source chunk = (l&3) ^ ((ldsrow>>1)&3) = (l&3)^((l>>3)&3).
  const int srow = wv * 16 + (l >> 2);          // 0..127 (qq=0 half)
  const int csw  = ((l & 3) ^ ((l >> 3) & 3)) * 8;
  const unsigned short* aSrc0 = Apk + (size_t)(brow + srow) * 2048 + csw;
  const unsigned short* aSrc1 = aSrc0 + (size_t)128 * 2048;
  // B: LDS row j <-> packed col p = nblk*256 + j ; decode to Wp row n
  int p0 = nblk * 256 + srow;
  int n0 = (((p0 >> 4) & 3) << 10) | ((p0 >> 6) << 4) | (p0 & 15);
  int p1 = p0 + 128;
  int n1 = (((p1 >> 4) & 3) << 10) | ((p1 >> 6) << 4) | (p1 & 15);
  const unsigned short* bSrc0 = Wp + (size_t)n0 * 2048 + csw;
  const unsigned short* bSrc1 = Wp + (size_t)n1 * 2048 + csw;

  f32x4 acc[8][4];                 // [m-frag][gate]
#pragma unroll
  for (int m = 0; m < 8; ++m)
#pragma unroll
    for (int g = 0; g < 4; ++g) acc[m][g] = (f32x4)0.0f;

  // --- prologue: stage S0 (tile0 K0), S1 (tile0 K1), S2 (tile1 K0)
  load_lds16(aSrc0 + 0,  &LDSu[0 + wv * 512]);
  load_lds16(aSrc1 + 0,  &LDSu[4096 + wv * 512]);
  load_lds16(bSrc0 + 0,  &LDSu[32768 + wv * 512]);
  load_lds16(bSrc1 + 0,  &LDSu[32768 + 4096 + wv * 512]);
  load_lds16(aSrc0 + 32, &LDSu[8192 + wv * 512]);
  load_lds16(aSrc1 + 32, &LDSu[8192 + 4096 + wv * 512]);
  load_lds16(bSrc0 + 32, &LDSu[32768 + 8192 + wv * 512]);
  load_lds16(bSrc1 + 32, &LDSu[32768 + 8192 + 4096 + wv * 512]);
  load_lds16(aSrc0 + 64, &LDSu[16384 + wv * 512]);
  load_lds16(aSrc1 + 64, &LDSu[16384 + 4096 + wv * 512]);
  load_lds16(bSrc0 + 64, &LDSu[32768 + 16384 + wv * 512]);
  load_lds16(bSrc1 + 64, &LDSu[32768 + 16384 + 4096 + wv * 512]);
  asm volatile("s_waitcnt vmcnt(4)" ::: "memory");   // S0,S1 landed; S2 in flight
  asm volatile("s_barrier" ::: "memory");

#pragma unroll 1
  for (int it = 0; it < 16; ++it) {
    const int k2 = it << 1;
    short8 bv[4];
    PHASE(0, 0, k2 + 1, 3, -1)   // compute S0 mh0 ; prefetch A of S3 <- tile 2i+1 K1
    PHASE(0, 1, k2 + 1, 3, -1)   // compute S0 mh1 ; prefetch B of S3
    PHASE(1, 0, k2 + 2, 0, -1)   // compute S1 mh0 ; prefetch A of S0 <- tile 2i+2 K0
    PHASE(1, 1, k2 + 2, 0, 8)    // compute S1 mh1 ; prefetch B of S0 ; wait S2
    PHASE(2, 0, k2 + 2, 1, -1)   // compute S2 mh0 ; prefetch A of S1 <- tile 2i+2 K1
    PHASE(2, 1, k2 + 2, 1, 8)    // compute S2 mh1 ; prefetch B of S1 ; wait S3
    PHASE(3, 0, k2 + 3, 2, -1)   // compute S3 mh0 ; prefetch A of S2 <- tile 2i+3 K0
    PHASE(3, 1, k2 + 3, 2, 4)    // compute S3 mh1 ; prefetch B of S2 ; wait S0,S1
  }

  // --- epilogue (register-local LSTM): frag g == gate g for the same h-col.
  const int colh = nblk * 64 + wc * 16 + rl;
  const float biasF = bF[colh], biasI = bI[colh];
  const float biasU = bU[colh], biasO = bO[colh];
  const int row0 = brow + wr * 128 + ((l >> 4) << 2);
#pragma unroll
  for (int m = 0; m < 8; ++m) {
#pragma unroll
    for (int r = 0; r < 4; ++r) {
      int row = row0 + m * 16 + r;
      size_t idx = (size_t)row * 1024 + colh;
      float f  = sigf(acc[m][0][r] + biasF);
      float i_ = sigf(acc[m][1][r] + biasI);
      float g_ = tanh_fast(acc[m][2][r] + biasU);
      float o_ = sigf(acc[m][3][r] + biasO);
      float cp = c_prev[idx];
      float cn = cp * f + i_ * g_;
      outH[idx] = o_ * tanh_fast(cn);
      outC[idx] = cn;
    }
  }
}

// ---------------------------------------------------------------------------
extern "C" void kernel_launch(void* const* d_in, const int* in_sizes, int n_in,
                              void* d_out, int out_size, void* d_ws, size_t ws_size,
                              hipStream_t stream) {
  const float* x      = (const float*)d_in[0];
  const float* h_prev = (const float*)d_in[1];
  const float* c_prev = (const float*)d_in[2];
  // d_in[3] = embed (unused by reference forward)
  const float* Wf = (const float*)d_in[4];
  const float* bf = (const float*)d_in[5];
  const float* Wi = (const float*)d_in[6];
  const float* bi = (const float*)d_in[7];
  const float* Wu = (const float*)d_in[8];
  const float* bu = (const float*)d_in[9];
  const float* Wo = (const float*)d_in[10];
  const float* bo = (const float*)d_in[11];

  unsigned short* Apk = (unsigned short*)d_ws;                                    // 32 MB
  unsigned short* Wp  = (unsigned short*)((char*)d_ws + (size_t)8192 * 2048 * 2); // 16 MB

  pack_a_kernel<<<8192, 256, 0, stream>>>(x, h_prev, Apk);
  pack_w_kernel<<<4096, 256, 0, stream>>>(Wf, Wi, Wu, Wo, Wp);

  // 128 KB dynamic LDS (above the 64 KB default cap)
  hipFuncSetAttribute((const void*)lstm_gemm_kernel,
                      hipFuncAttributeMaxDynamicSharedMemorySize, 131072);

  float* outH = (float*)d_out;
  float* outC = outH + (size_t)8192 * 1024;
  lstm_gemm_kernel<<<512, 512, 131072, stream>>>(Apk, Wp, c_prev,
                                                 bf, bi, bu, bo, outH, outC);
}